// Round 3
// baseline (1071.564 us; speedup 1.0000x reference)
//
#include <hip/hip_runtime.h>

// VQ quantize: z [16,256,64,64] f32, weight [1024,256] f32.
// Outputs (f32, concat): quantized [16,256,64,64], straight_through (== quantized
// numerically), indices [16,64,64] as float.
//
// The np reference computes d = ||z||^2 - 2 z.wT + ||w||^2 IN FP32, so every d is
// quantized to ulp(256) ~ 3.05e-5 and near-ties become exact fp32 ties resolved by
// np.argmin's first-index rule. We therefore:
//   pass 1: fast fp32 distance+argmin (true ordering), flag rows with margin < TAU
//           (TAU > 2x the max rounding shift, so unflagged rows are provably safe)
//   pass 2: for flagged rows, bit-replicate numpy's pipeline:
//           d_q = fl32( fl32(s1 - 2*m) + s2 ), s1/s2 = numpy pairwise fp32 sums of
//           squares (exact tree), m = fp64 dot (1e-14 << 3e-5 grid), first-index argmin.

#define NROWS 65536   // 16*64*64
#define DDIM 256
#define KCODES 1024
#define BM 128
#define BN 128
#define DC 32
#define TAU 1e-4f
#define RESCUE_CAP 16384

// numpy pairwise fp32 sum of 256 pre-rounded floats: split 128+128; each 128-block
// uses 8 accumulators r[j]=x[j]; r[j]+=x[i+j]; combine ((r0+r1)+(r2+r3))+((r4+r5)+(r6+r7)).
__device__ __forceinline__ float np_pairwise256(const float* x) {
    float half[2];
#pragma unroll
    for (int h = 0; h < 2; ++h) {
        const float* p = x + h * 128;
        float r[8];
#pragma unroll
        for (int j = 0; j < 8; ++j) r[j] = p[j];
        for (int i = 8; i < 128; i += 8)
#pragma unroll
            for (int j = 0; j < 8; ++j) r[j] = __fadd_rn(r[j], p[i + j]);
        half[h] = __fadd_rn(__fadd_rn(__fadd_rn(r[0], r[1]), __fadd_rn(r[2], r[3])),
                            __fadd_rn(__fadd_rn(r[4], r[5]), __fadd_rn(r[6], r[7])));
    }
    return __fadd_rn(half[0], half[1]);
}

// ---------------- kernel 1: s2[k] = numpy-replicated fp32 ||w_k||^2 ----------------
__global__ void wnorm_k(const float* __restrict__ w, float* __restrict__ wn) {
    int k = blockIdx.x * 64 + threadIdx.x;
    const float* wp = w + (size_t)k * DDIM;
    float sq[DDIM];
#pragma unroll 8
    for (int i = 0; i < DDIM; ++i) sq[i] = __fmul_rn(wp[i], wp[i]);
    wn[k] = np_pairwise256(sq);
}

// ---------------- kernel 2: fast fp32 distance + argmin (+ top-2 margin flag) --------
__launch_bounds__(256, 2)
__global__ void argmin_k(const float* __restrict__ z, const float* __restrict__ w,
                         const float* __restrict__ wn, float* __restrict__ idxf_out,
                         int* __restrict__ count, int* __restrict__ list) {
    __shared__ float zs[DC][BM];     // 16 KB
    __shared__ float wsm[DC][BN];    // 16 KB (permuted layout)

    const int t  = threadIdx.x;
    const int tx = t & 15;
    const int ty = t >> 4;
    const int n0 = blockIdx.x * BM;
    const float* zb = z + (size_t)(n0 >> 12) * 1048576 + (n0 & 4095);

    float bestv[8], best2v[8];
    int   besti[8];
#pragma unroll
    for (int i = 0; i < 8; ++i) { bestv[i] = 3.4e38f; best2v[i] = 3.4e38f; besti[i] = 0; }

    for (int cc = 0; cc < KCODES / BN; ++cc) {
        float acc[8][8];
#pragma unroll
        for (int i = 0; i < 8; ++i)
#pragma unroll
            for (int j = 0; j < 8; ++j) acc[i][j] = 0.f;

        for (int dc = 0; dc < DDIM / DC; ++dc) {
            __syncthreads();
            // stage Z: 128 rows x 32 dims -> zs[d][row]
#pragma unroll
            for (int i = 0; i < 4; ++i) {
                int id = t + i * 256;
                int d  = id >> 5;
                int r4 = (id & 31) << 2;
                float4 v = *reinterpret_cast<const float4*>(zb + (size_t)(dc * DC + d) * 4096 + r4);
                *reinterpret_cast<float4*>(&zs[d][r4]) = v;
            }
            // stage W: 128 codes x 32 dims -> wsm[d][perm(c)]
#pragma unroll
            for (int i = 0; i < 4; ++i) {
                int id = t + i * 256;
                int c  = id >> 3;
                int d4 = id & 7;
                float4 v = *reinterpret_cast<const float4*>(
                    w + (size_t)(cc * BN + c) * DDIM + dc * DC + d4 * 4);
                int blk = c >> 2;
                int e   = (((blk & 1) << 4) + (blk >> 1)) * 4 + (c & 3);
                wsm[d4 * 4 + 0][e] = v.x;
                wsm[d4 * 4 + 1][e] = v.y;
                wsm[d4 * 4 + 2][e] = v.z;
                wsm[d4 * 4 + 3][e] = v.w;
            }
            __syncthreads();
#pragma unroll 8
            for (int d = 0; d < DC; ++d) {
                float4 za  = *reinterpret_cast<const float4*>(&zs[d][ty * 8]);
                float4 zb4 = *reinterpret_cast<const float4*>(&zs[d][ty * 8 + 4]);
                float4 wa  = *reinterpret_cast<const float4*>(&wsm[d][tx * 4]);
                float4 wb  = *reinterpret_cast<const float4*>(&wsm[d][64 + tx * 4]);
                float zr[8] = {za.x, za.y, za.z, za.w, zb4.x, zb4.y, zb4.z, zb4.w};
                float wr[8] = {wa.x, wa.y, wa.z, wa.w, wb.x, wb.y, wb.z, wb.w};
#pragma unroll
                for (int i = 0; i < 8; ++i)
#pragma unroll
                    for (int j = 0; j < 8; ++j)
                        acc[i][j] = fmaf(zr[i], wr[j], acc[i][j]);
            }
        }
#pragma unroll
        for (int j = 0; j < 8; ++j) {
            int c = cc * BN + tx * 8 + j;
            float wnc = wn[c];
#pragma unroll
            for (int i = 0; i < 8; ++i) {
                float s = fmaf(-2.f, acc[i][j], wnc);
                if (s < bestv[i]) { best2v[i] = bestv[i]; bestv[i] = s; besti[i] = c; }
                else              { best2v[i] = fminf(best2v[i], s); }
            }
        }
    }

    // 16-lane butterfly reduce (16 threads of a row group are contiguous lanes)
#pragma unroll
    for (int i = 0; i < 8; ++i) {
        float bv = bestv[i], b2 = best2v[i];
        int   bi = besti[i];
#pragma unroll
        for (int m = 1; m < 16; m <<= 1) {
            float ov  = __shfl_xor(bv, m);
            int   oi  = __shfl_xor(bi, m);
            float ov2 = __shfl_xor(b2, m);
            if (ov < bv || (ov == bv && oi < bi)) { b2 = fminf(bv, ov2); bv = ov; bi = oi; }
            else                                  { b2 = fminf(b2, ov); }
        }
        if (tx == 0) {
            int n = n0 + ty * 8 + i;
            idxf_out[n] = (float)bi;
            if (b2 - bv < TAU) {               // quantization could change the winner
                int slot = atomicAdd(count, 1);
                if (slot < RESCUE_CAP) list[slot] = n;
            }
        }
    }
}

// ---------------- kernel 3: replicate numpy fp32 pipeline on flagged rows ----------
__global__ void rescue_k(const float* __restrict__ z, const float* __restrict__ w,
                         const float* __restrict__ s2, const int* __restrict__ count,
                         const int* __restrict__ list, float* __restrict__ idxf_out) {
    __shared__ float zsh[DDIM];
    __shared__ float rdv[256];
    __shared__ int   rid[256];
    const int t = threadIdx.x;
    int cnt = *count;
    if (cnt > RESCUE_CAP) cnt = RESCUE_CAP;

    for (int s = blockIdx.x; s < cnt; s += gridDim.x) {
        int n = list[s];
        __syncthreads();
        zsh[t] = z[(size_t)(n >> 12) * 1048576 + (size_t)t * 4096 + (n & 4095)];
        __syncthreads();
        // s1 = numpy pairwise fp32 sum of fl(z_i^2) — computed redundantly per thread
        float sq[DDIM];
#pragma unroll 8
        for (int i = 0; i < DDIM; ++i) sq[i] = __fmul_rn(zsh[i], zsh[i]);
        float s1 = np_pairwise256(sq);

        float bv = 3.4e38f;
        int   bi = 0;
#pragma unroll
        for (int k = 0; k < 4; ++k) {
            int c = t * 4 + k;
            const float4* wp = reinterpret_cast<const float4*>(w + (size_t)c * DDIM);
            double md = 0.0;
            for (int j = 0; j < DDIM / 4; ++j) {
                float4 wv = wp[j];
                md = fma((double)zsh[j * 4 + 0], (double)wv.x, md);
                md = fma((double)zsh[j * 4 + 1], (double)wv.y, md);
                md = fma((double)zsh[j * 4 + 2], (double)wv.z, md);
                md = fma((double)zsh[j * 4 + 3], (double)wv.w, md);
            }
            float t1 = (float)((double)s1 - 2.0 * md);   // = fl32(s1 - 2m)
            float dq = __fadd_rn(t1, s2[c]);             // = fl32(t1 + s2)
            if (dq < bv) { bv = dq; bi = c; }            // c ascending -> first index
        }
        rdv[t] = bv; rid[t] = bi;
        __syncthreads();
        for (int off = 128; off > 0; off >>= 1) {
            if (t < off) {
                if (rdv[t + off] < rdv[t] ||
                    (rdv[t + off] == rdv[t] && rid[t + off] < rid[t])) {
                    rdv[t] = rdv[t + off]; rid[t] = rid[t + off];
                }
            }
            __syncthreads();
        }
        if (t == 0) idxf_out[n] = (float)rid[0];
    }
}

// ---------------- kernel 4: gather quantized = weight[idx] into [b,c,h,w] x2 -------
__global__ void gather_k(const float* __restrict__ idxf, const float* __restrict__ w,
                         float* __restrict__ out0, float* __restrict__ out1) {
    int tid = blockIdx.x * 256 + threadIdx.x;
    int n   = tid & 65535;
    int c4  = tid >> 16;
    int code = (int)idxf[n];
    float4 v = *reinterpret_cast<const float4*>(w + (size_t)code * DDIM + c4 * 4);
    size_t off = (size_t)(n >> 12) * 1048576 + (size_t)c4 * 4 * 4096 + (n & 4095);
    out0[off]         = v.x;
    out0[off + 4096]  = v.y;
    out0[off + 8192]  = v.z;
    out0[off + 12288] = v.w;
    out1[off]         = v.x;
    out1[off + 4096]  = v.y;
    out1[off + 8192]  = v.z;
    out1[off + 12288] = v.w;
}

extern "C" void kernel_launch(void* const* d_in, const int* in_sizes, int n_in,
                              void* d_out, int out_size, void* d_ws, size_t ws_size,
                              hipStream_t stream) {
    const float* z = (const float*)d_in[0];   // 16*256*64*64
    const float* w = (const float*)d_in[1];   // 1024*256
    float* out    = (float*)d_out;
    float* out0   = out;                       // quantized
    float* out1   = out + 16777216;            // straight_through
    float* outidx = out + 33554432;            // indices as float

    float* wn    = (float*)d_ws;                          // 4 KB (np-replicated ||w||^2)
    int*   count = (int*)((char*)d_ws + 4096);
    int*   list  = (int*)((char*)d_ws + 8192);            // 64 KB

    hipMemsetAsync(count, 0, sizeof(int), stream);
    wnorm_k<<<KCODES / 64, 64, 0, stream>>>(w, wn);
    argmin_k<<<NROWS / BM, 256, 0, stream>>>(z, w, wn, outidx, count, list);
    rescue_k<<<1024, 256, 0, stream>>>(z, w, wn, count, list, outidx);
    gather_k<<<(NROWS * 64) / 256, 256, 0, stream>>>(outidx, w, out0, out1);
}